// Round 5
// baseline (25.950 us; speedup 1.0000x reference)
//
#include <hip/hip_runtime.h>
#include <math.h>

// FeedForwardQuantum, analytically collapsed circuit:
//   z_j = cos(theta_j) * cos(x.W1_j + b1_j)
//   ex[w] = prod_{j<=w} z_j (w>=1); ex[0] = prod_{j=1..7} z_j
//   out = relu(ex @ W2^T + b2)

constexpr int EMBED = 768;
constexpr int NQ    = 8;
constexpr int BLOCK = 256;            // 4 waves
constexpr int WAVES = 4;
constexpr int TPT   = 2;              // tokens per wave (concurrent) -- low VGPR, high occupancy
constexpr int TPB   = WAVES * TPT;    // 8 tokens/block

typedef float vfloat4 __attribute__((ext_vector_type(4)));

__global__ __launch_bounds__(BLOCK, 6) void ffq_kernel(
    const float* __restrict__ x,  const float* __restrict__ W1,
    const float* __restrict__ b1, const float* __restrict__ theta,
    const float* __restrict__ W2, const float* __restrict__ b2,
    float* __restrict__ out, int ntok)
{
    __shared__ float w2t[NQ][EMBED];          // transposed W2 (24 KB)
    __shared__ float zbuf[WAVES][TPT][NQ];    // per-wave z broadcast

    const int tid  = threadIdx.x;
    const int wave = tid >> 6;
    const int lane = tid & 63;

    const int t0 = (blockIdx.x * WAVES + wave) * TPT;
    int tk[TPT];
    #pragma unroll
    for (int it = 0; it < TPT; ++it) {
        int t = t0 + it; tk[it] = (t < ntok) ? t : (ntok - 1);   // clamp: benign dup
    }

    // ---- issue x loads FIRST: start HBM traffic before anything else ----
    const float4* x4 = (const float4*)x;
    float4 xv[TPT][3];
    #pragma unroll
    for (int it = 0; it < TPT; ++it)
        #pragma unroll
        for (int k = 0; k < 3; ++k)
            xv[it][k] = x4[(size_t)tk[it] * (EMBED / 4) + lane + 64 * k];

    // ---- stage W2 transposed: coalesced float4 reads, scalar scatter writes ----
    {
        const float4* W24 = (const float4*)W2;
        for (int i = tid; i < EMBED * NQ / 4; i += BLOCK) {
            const float4 v = W24[i];
            const int f = 4 * i;                 // flat = e*8 + q
            w2t[(f + 0) & 7][(f + 0) >> 3] = v.x;
            w2t[(f + 1) & 7][(f + 1) >> 3] = v.y;
            w2t[(f + 2) & 7][(f + 2) >> 3] = v.z;
            w2t[(f + 3) & 7][(f + 3) >> 3] = v.w;
        }
    }

    const int q_own = lane & 7;
    const float costh = __cosf(theta[q_own]);
    const float b1q   = b1[q_own];

    __syncthreads();   // w2t ready

    // ---- GEMM1 partials: W1 from global (L1/L2-resident), shared across tokens ----
    const float4* W14 = (const float4*)W1;
    float acc[TPT][NQ];
    #pragma unroll
    for (int it = 0; it < TPT; ++it)
        #pragma unroll
        for (int q = 0; q < NQ; ++q) acc[it][q] = 0.f;

    #pragma unroll
    for (int k = 0; k < 3; ++k) {
        const int idx = lane + 64 * k;
        #pragma unroll
        for (int q = 0; q < NQ; ++q) {
            const float4 w = W14[q * (EMBED / 4) + idx];
            #pragma unroll
            for (int it = 0; it < TPT; ++it) {
                acc[it][q] = fmaf(xv[it][k].x, w.x, fmaf(xv[it][k].y, w.y,
                             fmaf(xv[it][k].z, w.z, fmaf(xv[it][k].w, w.w, acc[it][q]))));
            }
        }
    }

    // ---- packed reduce: 10 shuffles/token -> lane holds full sum for q = lane&7 ----
    const bool c0 = lane & 1, c1 = lane & 2, c2 = lane & 4;
    float S[TPT];
    #pragma unroll
    for (int it = 0; it < TPT; ++it) {
        float k0 = c0 ? acc[it][1] : acc[it][0], g0 = c0 ? acc[it][0] : acc[it][1];
        float k1 = c0 ? acc[it][3] : acc[it][2], g1 = c0 ? acc[it][2] : acc[it][3];
        float k2 = c0 ? acc[it][5] : acc[it][4], g2 = c0 ? acc[it][4] : acc[it][5];
        float k3 = c0 ? acc[it][7] : acc[it][6], g3 = c0 ? acc[it][6] : acc[it][7];
        float v0 = k0 + __shfl_xor(g0, 1, 64);
        float v1 = k1 + __shfl_xor(g1, 1, 64);
        float v2 = k2 + __shfl_xor(g2, 1, 64);
        float v3 = k3 + __shfl_xor(g3, 1, 64);
        float ka = c1 ? v1 : v0, ga = c1 ? v0 : v1;
        float kb = c1 ? v3 : v2, gb = c1 ? v2 : v3;
        float u0 = ka + __shfl_xor(ga, 2, 64);
        float u1 = kb + __shfl_xor(gb, 2, 64);
        float kc = c2 ? u1 : u0, gc = c2 ? u0 : u1;
        float s  = kc + __shfl_xor(gc, 4, 64);
        s += __shfl_xor(s, 8, 64);
        s += __shfl_xor(s, 16, 64);
        s += __shfl_xor(s, 32, 64);
        S[it] = s;   // full sum of q_in[token it][q_own]
    }

    // ---- one cosf per lane; octet parity selects which token it publishes ----
    const int osel = (lane >> 3) & (TPT - 1);
    const float Ssel = osel ? S[1] : S[0];
    const float zval = costh * __cosf(Ssel + b1q);
    zbuf[wave][osel][q_own] = zval;    // 4 octets per token write identical values

    // ---- read back sorted z[8] per token (broadcast b128), prefix products ----
    float ex[TPT][NQ];
    #pragma unroll
    for (int it = 0; it < TPT; ++it) {
        const float4 za = ((const float4*)zbuf[wave][it])[0];
        const float4 zb = ((const float4*)zbuf[wave][it])[1];
        const float zq[NQ] = { za.x, za.y, za.z, za.w, zb.x, zb.y, zb.z, zb.w };
        float p = zq[0];
        #pragma unroll
        for (int q = 1; q < NQ; ++q) { p *= zq[q]; ex[it][q] = p; }
        float sfx = zq[1];
        #pragma unroll
        for (int q = 2; q < NQ; ++q) sfx *= zq[q];
        ex[it][0] = sfx;
    }

    // ---- GEMM2 + bias + relu: conflict-free b128 LDS reads, NT float4 stores ----
    const float4* b24 = (const float4*)b2;
    #pragma unroll
    for (int k = 0; k < 3; ++k) {
        const int idx = lane + 64 * k;
        const float4 bb = b24[idx];
        float4 r[TPT];
        #pragma unroll
        for (int it = 0; it < TPT; ++it) r[it] = bb;
        #pragma unroll
        for (int q = 0; q < NQ; ++q) {
            const float4 w = ((const float4*)&w2t[q][0])[idx];
            #pragma unroll
            for (int it = 0; it < TPT; ++it) {
                r[it].x = fmaf(ex[it][q], w.x, r[it].x);
                r[it].y = fmaf(ex[it][q], w.y, r[it].y);
                r[it].z = fmaf(ex[it][q], w.z, r[it].z);
                r[it].w = fmaf(ex[it][q], w.w, r[it].w);
            }
        }
        #pragma unroll
        for (int it = 0; it < TPT; ++it) {
            vfloat4 o = { fmaxf(r[it].x, 0.f), fmaxf(r[it].y, 0.f),
                          fmaxf(r[it].z, 0.f), fmaxf(r[it].w, 0.f) };
            __builtin_nontemporal_store(o, (vfloat4*)(out + (size_t)tk[it] * EMBED) + idx);
        }
    }
}

extern "C" void kernel_launch(void* const* d_in, const int* in_sizes, int n_in,
                              void* d_out, int out_size, void* d_ws, size_t ws_size,
                              hipStream_t stream) {
    const float* x     = (const float*)d_in[0];
    const float* W1    = (const float*)d_in[1];
    const float* b1    = (const float*)d_in[2];
    const float* theta = (const float*)d_in[3];
    const float* W2    = (const float*)d_in[4];
    const float* b2    = (const float*)d_in[5];
    float* out = (float*)d_out;

    const int ntok = in_sizes[0] / EMBED;          // 16384
    const int grid = (ntok + TPB - 1) / TPB;       // 2048
    hipLaunchKernelGGL(ffq_kernel, dim3(grid), dim3(BLOCK), 0, stream,
                       x, W1, b1, theta, W2, b2, out, ntok);
}